// Round 2
// baseline (4026.938 us; speedup 1.0000x reference)
//
#include <hip/hip_runtime.h>
#include <hip/hip_fp16.h>
#include <cstdint>
#include <cstddef>

// Problem dims
#define B_    64
#define T_    256
#define D_    512
#define U_    500
#define UP_   512            // padded units
#define NCOL_ 2048           // 4*UP_
#define K_    1024           // D_ + UP_

typedef _Float16 f16x8 __attribute__((ext_vector_type(8)));
typedef float    f32x4 __attribute__((ext_vector_type(4)));

// ---- workspace layout (bytes) ----
#define OFF_X   0ull                         // x fp16: 64*256*512*2        = 16777216
#define OFF_W   16777216ull                  // Wcomb fp16: 2*2048*1024*2   = 8388608
#define OFF_B   25165824ull                  // bcomb f32: 2*2048*4         = 16384
#define OFF_H   25182208ull                  // h_buf fp16: 8*2*16*512*2    = 262144
#define OFF_C   25444352ull                  // counters: 8*256*4           = 8192

// ---- LDS layout (bytes) ----
#define LW 0                 // W slice: 64 cols * 2048B (col-major, swizzled)
#define LX 131072            // x tile: 16 rows * 1024B (swizzled)
#define LH 147456            // h tile: 16 rows * 1024B (swizzled)
#define LZ LX                // z exchange aliases x region: 4*272*4 = 4352B
#define LDS_BYTES 163840

#define GLD_LDS16(g, l) \
  __builtin_amdgcn_global_load_lds((const __attribute__((address_space(1))) void*)(g), \
                                   (__attribute__((address_space(3))) void*)(l), 16, 0, 0)

// ============================ prep kernels ============================

// cast x (f32) -> fp16, linear layout
__global__ void prep_x(const float* __restrict__ x, _Float16* __restrict__ xf) {
  size_t base = ((size_t)blockIdx.x * 256 + threadIdx.x) * 8;  // grid covers exactly B*T*D/8
  const float4* p = (const float4*)(x + base);
  float4 a = p[0], b = p[1];
  f16x8 v;
  v[0] = (_Float16)a.x; v[1] = (_Float16)a.y; v[2] = (_Float16)a.z; v[3] = (_Float16)a.w;
  v[4] = (_Float16)b.x; v[5] = (_Float16)b.y; v[6] = (_Float16)b.z; v[7] = (_Float16)b.w;
  *(f16x8*)(xf + base) = v;
}

// Build combined weights Wcomb[dir][col][k] fp16 (col-major over k), col = ut*64 + g*16 + du,
// rows k<512 = Wk, k in [512,1012) = Wr, rest zero-padded.  Also bcomb.
__global__ void prep_w(const float* __restrict__ Wkf, const float* __restrict__ Wrf,
                       const float* __restrict__ Wkb, const float* __restrict__ Wrb,
                       const float* __restrict__ bf,  const float* __restrict__ bb,
                       _Float16* __restrict__ Wc, float* __restrict__ bcomb) {
  size_t gid = (size_t)blockIdx.x * 256 + threadIdx.x;   // 0 .. 524287, 8 k's each
  int dir = (int)(gid >> 18);
  int rem = (int)(gid & 262143);
  int col = rem >> 7;
  int k0  = (rem & 127) << 3;
  const float* Wk = dir ? Wkb : Wkf;
  const float* Wr = dir ? Wrb : Wrf;
  int g = (col >> 4) & 3, du = col & 15, utc = col >> 6;
  int ug = utc * 16 + du;
  bool valid = (ug < U_);
  int c4 = g * U_ + ug;
  f16x8 out;
#pragma unroll
  for (int kk = 0; kk < 8; ++kk) {
    int k = k0 + kk;
    float v = 0.f;
    if (valid) {
      if (k < D_) v = Wk[(size_t)k * (4 * U_) + c4];
      else { int u = k - D_; if (u < U_) v = Wr[(size_t)u * (4 * U_) + c4]; }
    }
    out[kk] = (_Float16)v;
  }
  *(f16x8*)(Wc + ((size_t)dir * NCOL_ + col) * K_ + k0) = out;

  if (gid < 4096) {  // bcomb[dir][col]
    int d2 = (int)(gid >> 11), c2 = (int)(gid & 2047);
    int g2 = (c2 >> 4) & 3, du2 = c2 & 15, ut2 = c2 >> 6;
    int ug2 = ut2 * 16 + du2;
    const float* bs = d2 ? bb : bf;
    bcomb[gid] = (ug2 < U_) ? bs[g2 * U_ + ug2] : 0.f;
  }
}

// init h_buf buffer index 1 (read by scan step t=0) from h0 inputs
__global__ void prep_hb(const float* __restrict__ hf, const float* __restrict__ hb,
                        _Float16* __restrict__ hbuf) {
  int idx = blockIdx.x * 256 + threadIdx.x;    // < 65536
  int dir = idx >> 15;
  int rem = idx & 32767;
  int bt = rem >> 13, r = (rem >> 9) & 15, u = rem & 511;
  const float* h0 = dir ? hb : hf;
  float v = (u < U_) ? h0[(size_t)(bt * 16 + r) * U_ + u] : 0.f;
  hbuf[((size_t)((dir * 4 + bt) * 2 + 1) * 16 + r) * UP_ + u] = (_Float16)v;
}

// ============================ persistent scan ============================
// 256 blocks (1/CU), 256 threads. Block = (dir, bt, ut): 16 batch rows x 16 units.
// Group (dir,bt) = 32 blocks exchanges h via global h_buf + per-step arrive counters.
__global__ __launch_bounds__(256, 1) void lstm_scan(
    const _Float16* __restrict__ xf, const _Float16* __restrict__ Wc,
    const float* __restrict__ bc, const float* __restrict__ cf,
    const float* __restrict__ cb, _Float16* __restrict__ hbuf,
    int* __restrict__ cnt, float* __restrict__ y)
{
  extern __shared__ __align__(16) char lds[];
  const int tid  = threadIdx.x;
  const int lane = tid & 63;
  const int w    = tid >> 6;        // wave id == gate id (i,f,g,o)
  const int bid  = blockIdx.x;
  const int grp  = bid & 7;         // group id -> same XCD under round-robin (perf only)
  const int dir  = grp >> 2;
  const int bt   = grp & 3;
  const int ut   = bid >> 3;

  // ---- prologue: W slice -> LDS (col-major, 16B-chunk XOR swizzle) ----
  {
    const int4* wsrc = (const int4*)(Wc + ((size_t)dir * NCOL_ + (size_t)ut * 64) * K_);
    for (int it = 0; it < 32; ++it) {
      int idx = it * 256 + tid;
      int j = idx >> 7, ch = idx & 127;
      int4 v = wsrc[j * 128 + ch];
      *(int4*)(lds + LW + (size_t)j * 2048 + ((ch ^ (j & 7)) << 4)) = v;
    }
  }
  const float bias = bc[dir * NCOL_ + ut * 64 + w * 16 + (lane & 15)];
  const int r0 = tid >> 4, du0 = tid & 15;
  const int ug0 = ut * 16 + du0;
  const float* cin = dir ? cb : cf;
  float c = (ug0 < U_) ? cin[(size_t)(bt * 16 + r0) * U_ + ug0] : 0.f;
  __syncthreads();

  const int gi = dir * 4 + bt;
  int* cbase = cnt + gi * 256;
  _Float16* hb = hbuf + (size_t)gi * 2 * 16 * UP_;
  const int colj = w * 16 + (lane & 15);
  const int arow = lane & 15;
  const int kg   = lane >> 4;
  const char* wcol = lds + LW + (size_t)colj * 2048;
  const char* xrow = lds + LX + (size_t)arow * 1024;
  const char* hrow = lds + LH + (size_t)arow * 1024;
  const int cswz = colj & 7, aswz = arow & 7;
  float* zw = (float*)(lds + LZ);

  for (int t = 0; t < T_; ++t) {
    const int t_x = dir ? (T_ - 1 - t) : t;

    // stage x tile (issue early; overlaps the poll). wave w stages rows 4w..4w+3
    for (int rr = 0; rr < 4; ++rr) {
      int r = w * 4 + rr;
      const char* src = (const char*)(xf + ((size_t)(bt * 16 + r) * T_ + t_x) * D_)
                        + ((lane ^ (r & 7)) << 4);
      GLD_LDS16(src, lds + LX + r * 1024);
    }

    if (t > 0) {
      if (tid == 0) {
        int* cp = cbase + (t - 1);
        while (__hip_atomic_load(cp, __ATOMIC_RELAXED, __HIP_MEMORY_SCOPE_AGENT) < 32)
          __builtin_amdgcn_s_sleep(2);
      }
      __syncthreads();
      __builtin_amdgcn_fence(__ATOMIC_ACQUIRE, "agent");
    }

    // stage h tile (double-buffered: read buf (t+1)&1)
    {
      const _Float16* hsrc = hb + (size_t)((t + 1) & 1) * 16 * UP_;
      for (int rr = 0; rr < 4; ++rr) {
        int r = w * 4 + rr;
        const char* src = (const char*)(hsrc + (size_t)r * UP_) + ((lane ^ (r & 7)) << 4);
        GLD_LDS16(src, lds + LH + r * 1024);
      }
    }
    __syncthreads();   // drains vmcnt -> x_lds & h_lds ready

    // ---- MFMA: z tile [16 rows x 16 cols] for gate w, K = 512(x) + 512(h) ----
    f32x4 ax0 = {0.f,0.f,0.f,0.f}, ax1 = {0.f,0.f,0.f,0.f};
    f32x4 ah0 = {0.f,0.f,0.f,0.f}, ah1 = {0.f,0.f,0.f,0.f};
#pragma unroll
    for (int ks = 0; ks < 16; ++ks) {
      int ch = ks * 4 + kg;
      f16x8 a = *(const f16x8*)(xrow + ((ch ^ aswz) << 4));
      f16x8 b = *(const f16x8*)(wcol + ((ch ^ cswz) << 4));
      if (ks & 1) ax1 = __builtin_amdgcn_mfma_f32_16x16x32_f16(a, b, ax1, 0, 0, 0);
      else        ax0 = __builtin_amdgcn_mfma_f32_16x16x32_f16(a, b, ax0, 0, 0, 0);
    }
#pragma unroll
    for (int ks = 0; ks < 16; ++ks) {
      int ch = ks * 4 + kg;
      f16x8 a = *(const f16x8*)(hrow + ((ch ^ aswz) << 4));
      f16x8 b = *(const f16x8*)(wcol + (((64 + ch) ^ cswz) << 4));
      if (ks & 1) ah1 = __builtin_amdgcn_mfma_f32_16x16x32_f16(a, b, ah1, 0, 0, 0);
      else        ah0 = __builtin_amdgcn_mfma_f32_16x16x32_f16(a, b, ah0, 0, 0, 0);
    }
    __syncthreads();   // all x_lds reads done -> z region (alias) writable

    // write z tile: row=(kg*4+q), col=lane&15; stride-17 rows (bank-conflict-free)
#pragma unroll
    for (int q = 0; q < 4; ++q) {
      float zv = ax0[q] + ax1[q] + ah0[q] + ah1[q] + bias;
      zw[w * 272 + (kg * 4 + q) * 17 + (lane & 15)] = zv;
    }
    __syncthreads();

    // ---- gate combine: thread -> (row r0, unit du0), c in register ----
    {
      const float* zr = (const float*)(lds + LZ);
      int zb = r0 * 17 + du0;
      float zi = zr[zb], zf = zr[272 + zb], zg = zr[544 + zb], zo = zr[816 + zb];
      float ig = 1.f / (1.f + __expf(-zi));
      float fg = 1.f / (1.f + __expf(-zf));
      float e2 = __expf(2.f * zg);
      float gg = (e2 - 1.f) / (e2 + 1.f);
      float og = 1.f / (1.f + __expf(-zo));
      c = fg * c + ig * gg;
      float ec = __expf(2.f * c);
      float th = (ec - 1.f) / (ec + 1.f);
      float h = og * th;
      if (ug0 < U_)
        y[((size_t)(bt * 16 + r0) * T_ + t_x) * (2 * U_) + dir * U_ + ug0] = h;
      hb[(size_t)(t & 1) * 16 * UP_ + (size_t)r0 * UP_ + ug0] = (_Float16)h;
    }
    __syncthreads();   // all global h stores complete (vmcnt drained per wave)

    if (tid == 0) {
      __builtin_amdgcn_fence(__ATOMIC_RELEASE, "agent");
      __hip_atomic_fetch_add(cbase + t, 1, __ATOMIC_RELAXED, __HIP_MEMORY_SCOPE_AGENT);
    }
  }
}

// ============================ launcher ============================
extern "C" void kernel_launch(void* const* d_in, const int* in_sizes, int n_in,
                              void* d_out, int out_size, void* d_ws, size_t ws_size,
                              hipStream_t stream) {
  (void)in_sizes; (void)n_in; (void)out_size; (void)ws_size;
  const float* x    = (const float*)d_in[0];
  const float* h_f  = (const float*)d_in[1];
  const float* c_f  = (const float*)d_in[2];
  const float* h_b  = (const float*)d_in[3];
  const float* c_b  = (const float*)d_in[4];
  const float* Wk_f = (const float*)d_in[5];
  const float* Wr_f = (const float*)d_in[6];
  const float* b_f  = (const float*)d_in[7];
  const float* Wk_b = (const float*)d_in[8];
  const float* Wr_b = (const float*)d_in[9];
  const float* b_b  = (const float*)d_in[10];

  char* ws = (char*)d_ws;
  _Float16* xf    = (_Float16*)(ws + OFF_X);
  _Float16* Wc    = (_Float16*)(ws + OFF_W);
  float*    bcomb = (float*)   (ws + OFF_B);
  _Float16* hbuf  = (_Float16*)(ws + OFF_H);
  int*      cnt   = (int*)     (ws + OFF_C);
  float*    y     = (float*)d_out;

  (void)hipMemsetAsync(ws + OFF_C, 0, 8192, stream);
  prep_x<<<4096, 256, 0, stream>>>(x, xf);
  prep_w<<<2048, 256, 0, stream>>>(Wk_f, Wr_f, Wk_b, Wr_b, b_f, b_b, Wc, bcomb);
  prep_hb<<<256, 256, 0, stream>>>(h_f, h_b, hbuf);

  static bool attr_done = false;
  if (!attr_done) {
    (void)hipFuncSetAttribute((const void*)lstm_scan,
                              hipFuncAttributeMaxDynamicSharedMemorySize, LDS_BYTES);
    attr_done = true;
  }
  lstm_scan<<<256, 256, LDS_BYTES, stream>>>(xf, Wc, bcomb, c_f, c_b, hbuf, cnt, y);
}

// Round 3
// 1328.167 us; speedup vs baseline: 3.0320x; 3.0320x over previous
//
#include <hip/hip_runtime.h>
#include <hip/hip_fp16.h>
#include <cstdint>
#include <cstddef>

// Problem dims
#define B_    64
#define T_    256
#define D_    512
#define U_    500
#define UP_   512            // padded units
#define NCOL_ 2048           // 4*UP_
#define K_    1024           // D_ + UP_

typedef _Float16 f16x8 __attribute__((ext_vector_type(8)));
typedef float    f32x4 __attribute__((ext_vector_type(4)));

// ---- workspace layout (bytes) ----
#define OFF_X   0ull                         // x fp16: 64*256*512*2        = 16777216
#define OFF_W   16777216ull                  // Wcomb fp16: 2*2048*1024*2   = 8388608
#define OFF_B   25165824ull                  // bcomb f32: 2*2048*4         = 16384
#define OFF_H   25182208ull                  // h_buf fp16: 8*2*16*512*2    = 262144
#define OFF_C   25444352ull                  // counters: 8*256*4           = 8192

// ---- LDS layout (bytes) ----
#define LW 0                 // W slice: 64 cols * 2048B (col-major, swizzled)
#define LX 131072            // x tile: 16 rows * 1024B (swizzled)           16KB
#define LZ 147456            // z exchange: 4*272*4 = 4352B
#define LDS_BYTES 151808

#define GLD_LDS16(g, l) \
  __builtin_amdgcn_global_load_lds((const __attribute__((address_space(1))) void*)(g), \
                                   (__attribute__((address_space(3))) void*)(l), 16, 0, 0)

// ============================ prep kernels ============================

__global__ void prep_x(const float* __restrict__ x, _Float16* __restrict__ xf) {
  size_t base = ((size_t)blockIdx.x * 256 + threadIdx.x) * 8;
  const float4* p = (const float4*)(x + base);
  float4 a = p[0], b = p[1];
  f16x8 v;
  v[0] = (_Float16)a.x; v[1] = (_Float16)a.y; v[2] = (_Float16)a.z; v[3] = (_Float16)a.w;
  v[4] = (_Float16)b.x; v[5] = (_Float16)b.y; v[6] = (_Float16)b.z; v[7] = (_Float16)b.w;
  *(f16x8*)(xf + base) = v;
}

__global__ void prep_w(const float* __restrict__ Wkf, const float* __restrict__ Wrf,
                       const float* __restrict__ Wkb, const float* __restrict__ Wrb,
                       const float* __restrict__ bf,  const float* __restrict__ bb,
                       _Float16* __restrict__ Wc, float* __restrict__ bcomb) {
  size_t gid = (size_t)blockIdx.x * 256 + threadIdx.x;
  int dir = (int)(gid >> 18);
  int rem = (int)(gid & 262143);
  int col = rem >> 7;
  int k0  = (rem & 127) << 3;
  const float* Wk = dir ? Wkb : Wkf;
  const float* Wr = dir ? Wrb : Wrf;
  int g = (col >> 4) & 3, du = col & 15, utc = col >> 6;
  int ug = utc * 16 + du;
  bool valid = (ug < U_);
  int c4 = g * U_ + ug;
  f16x8 out;
#pragma unroll
  for (int kk = 0; kk < 8; ++kk) {
    int k = k0 + kk;
    float v = 0.f;
    if (valid) {
      if (k < D_) v = Wk[(size_t)k * (4 * U_) + c4];
      else { int u = k - D_; if (u < U_) v = Wr[(size_t)u * (4 * U_) + c4]; }
    }
    out[kk] = (_Float16)v;
  }
  *(f16x8*)(Wc + ((size_t)dir * NCOL_ + col) * K_ + k0) = out;

  if (gid < 4096) {
    int d2 = (int)(gid >> 11), c2 = (int)(gid & 2047);
    int g2 = (c2 >> 4) & 3, du2 = c2 & 15, ut2 = c2 >> 6;
    int ug2 = ut2 * 16 + du2;
    const float* bs = d2 ? bb : bf;
    bcomb[gid] = (ug2 < U_) ? bs[g2 * U_ + ug2] : 0.f;
  }
}

__global__ void prep_hb(const float* __restrict__ hf, const float* __restrict__ hb,
                        _Float16* __restrict__ hbuf) {
  int idx = blockIdx.x * 256 + threadIdx.x;    // < 65536
  int dir = idx >> 15;
  int rem = idx & 32767;
  int bt = rem >> 13, r = (rem >> 9) & 15, u = rem & 511;
  const float* h0 = dir ? hb : hf;
  float v = (u < U_) ? h0[(size_t)(bt * 16 + r) * U_ + u] : 0.f;
  hbuf[((size_t)((dir * 4 + bt) * 2 + 1) * 16 + r) * UP_ + u] = (_Float16)v;
}

// ============================ persistent scan ============================
// 256 blocks (1/CU), 256 threads. Block = (dir, bt, ut): 16 batch rows x 16 units.
// Group (dir,bt) = 32 blocks. NO fences: h published via agent-scope relaxed
// atomic stores (coherent-point write-through), consumed via agent-scope
// relaxed atomic loads straight into MFMA fragments. Counter ordered by
// __syncthreads' vmcnt drain.
__global__ __launch_bounds__(256, 1) void lstm_scan(
    const _Float16* __restrict__ xf, const _Float16* __restrict__ Wc,
    const float* __restrict__ bc, const float* __restrict__ cf,
    const float* __restrict__ cb, _Float16* __restrict__ hbuf,
    int* __restrict__ cnt, float* __restrict__ y)
{
  extern __shared__ __align__(16) char lds[];
  const int tid  = threadIdx.x;
  const int lane = tid & 63;
  const int w    = tid >> 6;        // wave id == gate id (i,f,g,o)
  const int bid  = blockIdx.x;
  const int grp  = bid & 7;         // group -> same XCD under round-robin (perf only)
  const int dir  = grp >> 2;
  const int bt   = grp & 3;
  const int ut   = bid >> 3;

  // ---- prologue: W slice -> LDS (col-major, 16B-chunk XOR swizzle) ----
  {
    const int4* wsrc = (const int4*)(Wc + ((size_t)dir * NCOL_ + (size_t)ut * 64) * K_);
    for (int it = 0; it < 32; ++it) {
      int idx = it * 256 + tid;
      int j = idx >> 7, ch = idx & 127;
      int4 v = wsrc[j * 128 + ch];
      *(int4*)(lds + LW + (size_t)j * 2048 + ((ch ^ (j & 7)) << 4)) = v;
    }
  }
  const float bias = bc[dir * NCOL_ + ut * 64 + w * 16 + (lane & 15)];
  const int r0 = tid >> 4, du0 = tid & 15;
  const int ug0 = ut * 16 + du0;
  const float* cin = dir ? cb : cf;
  float c = (ug0 < U_) ? cin[(size_t)(bt * 16 + r0) * U_ + ug0] : 0.f;
  __syncthreads();

  const int gi = dir * 4 + bt;
  int* cbase = cnt + gi * 256;
  _Float16* hb = hbuf + (size_t)gi * 2 * 16 * UP_;
  const int colj = w * 16 + (lane & 15);
  const int arow = lane & 15;
  const int kg   = lane >> 4;
  const char* wcol = lds + LW + (size_t)colj * 2048;
  const char* xrow = lds + LX + (size_t)arow * 1024;
  const int cswz = colj & 7, aswz = arow & 7;
  float* zw = (float*)(lds + LZ);

  for (int t = 0; t < T_; ++t) {
    const int t_x = dir ? (T_ - 1 - t) : t;

    // stage x tile (issue early; overlaps the poll). wave w stages rows 4w..4w+3
    for (int rr = 0; rr < 4; ++rr) {
      int r = w * 4 + rr;
      const char* src = (const char*)(xf + ((size_t)(bt * 16 + r) * T_ + t_x) * D_)
                        + ((lane ^ (r & 7)) << 4);
      GLD_LDS16(src, lds + LX + r * 1024);
    }

    if (t > 0) {
      if (tid == 0) {
        int* cp = cbase + (t - 1);
        while (__hip_atomic_load(cp, __ATOMIC_RELAXED, __HIP_MEMORY_SCOPE_AGENT) < 32)
          __builtin_amdgcn_s_sleep(2);
      }
    }
    __syncthreads();   // x LDS ready (vmcnt drained); z region free; h[t-1] published

    // ---- h fragments: direct agent-coherent loads into registers ----
    const unsigned long long* hr =
        (const unsigned long long*)(hb + (size_t)((t + 1) & 1) * 16 * UP_);
    f16x8 hfrag[16];
#pragma unroll
    for (int ks = 0; ks < 16; ++ks) {
      int ch = ks * 4 + kg;
      union { unsigned long long u[2]; f16x8 v; } tmp;
      tmp.u[0] = __hip_atomic_load(hr + arow * 128 + ch * 2,
                                   __ATOMIC_RELAXED, __HIP_MEMORY_SCOPE_AGENT);
      tmp.u[1] = __hip_atomic_load(hr + arow * 128 + ch * 2 + 1,
                                   __ATOMIC_RELAXED, __HIP_MEMORY_SCOPE_AGENT);
      hfrag[ks] = tmp.v;
    }

    // ---- MFMA: z tile [16 x 16] for gate w, K = 512(x) + 512(h) ----
    f32x4 ax0 = {0.f,0.f,0.f,0.f}, ax1 = {0.f,0.f,0.f,0.f};
    f32x4 ah0 = {0.f,0.f,0.f,0.f}, ah1 = {0.f,0.f,0.f,0.f};
#pragma unroll
    for (int ks = 0; ks < 16; ++ks) {
      int ch = ks * 4 + kg;
      f16x8 a = *(const f16x8*)(xrow + ((ch ^ aswz) << 4));
      f16x8 b = *(const f16x8*)(wcol + ((ch ^ cswz) << 4));
      if (ks & 1) ax1 = __builtin_amdgcn_mfma_f32_16x16x32_f16(a, b, ax1, 0, 0, 0);
      else        ax0 = __builtin_amdgcn_mfma_f32_16x16x32_f16(a, b, ax0, 0, 0, 0);
    }
#pragma unroll
    for (int ks = 0; ks < 16; ++ks) {
      int ch = ks * 4 + kg;
      f16x8 b = *(const f16x8*)(wcol + (((64 + ch) ^ cswz) << 4));
      if (ks & 1) ah1 = __builtin_amdgcn_mfma_f32_16x16x32_f16(hfrag[ks], b, ah1, 0, 0, 0);
      else        ah0 = __builtin_amdgcn_mfma_f32_16x16x32_f16(hfrag[ks], b, ah0, 0, 0, 0);
    }

    // write z tile: row=(kg*4+q), col=lane&15; stride-17 rows
#pragma unroll
    for (int q = 0; q < 4; ++q) {
      float zv = ax0[q] + ax1[q] + ah0[q] + ah1[q] + bias;
      zw[w * 272 + (kg * 4 + q) * 17 + (lane & 15)] = zv;
    }
    __syncthreads();

    // ---- gate combine: thread -> (row r0, unit du0), c in register ----
    {
      const float* zr = (const float*)(lds + LZ);
      int zb = r0 * 17 + du0;
      float zi = zr[zb], zf = zr[272 + zb], zg = zr[544 + zb], zo = zr[816 + zb];
      float ig = 1.f / (1.f + __expf(-zi));
      float fg = 1.f / (1.f + __expf(-zf));
      float e2 = __expf(2.f * zg);
      float gg = (e2 - 1.f) / (e2 + 1.f);
      float og = 1.f / (1.f + __expf(-zo));
      c = fg * c + ig * gg;
      float ec = __expf(2.f * c);
      float th = (ec - 1.f) / (ec + 1.f);
      float h = og * th;
      if (ug0 < U_)
        y[((size_t)(bt * 16 + r0) * T_ + t_x) * (2 * U_) + dir * U_ + ug0] = h;

      // publish h: pack pairs, agent-scope coherent 4B stores
      float hpart = __shfl_xor(h, 1, 64);
      if ((du0 & 1) == 0) {
        union { _Float16 f[2]; unsigned u; } pk;
        pk.f[0] = (_Float16)h; pk.f[1] = (_Float16)hpart;
        unsigned* hbw = (unsigned*)(hb + (size_t)(t & 1) * 16 * UP_);
        __hip_atomic_store(hbw + r0 * 256 + (ug0 >> 1), pk.u,
                           __ATOMIC_RELAXED, __HIP_MEMORY_SCOPE_AGENT);
      }
    }
    __syncthreads();   // drains every wave's vmcnt -> coherent h stores complete

    if (tid == 0)
      __hip_atomic_fetch_add(cbase + t, 1, __ATOMIC_RELAXED, __HIP_MEMORY_SCOPE_AGENT);
  }
}

// ============================ launcher ============================
extern "C" void kernel_launch(void* const* d_in, const int* in_sizes, int n_in,
                              void* d_out, int out_size, void* d_ws, size_t ws_size,
                              hipStream_t stream) {
  (void)in_sizes; (void)n_in; (void)out_size; (void)ws_size;
  const float* x    = (const float*)d_in[0];
  const float* h_f  = (const float*)d_in[1];
  const float* c_f  = (const float*)d_in[2];
  const float* h_b  = (const float*)d_in[3];
  const float* c_b  = (const float*)d_in[4];
  const float* Wk_f = (const float*)d_in[5];
  const float* Wr_f = (const float*)d_in[6];
  const float* b_f  = (const float*)d_in[7];
  const float* Wk_b = (const float*)d_in[8];
  const float* Wr_b = (const float*)d_in[9];
  const float* b_b  = (const float*)d_in[10];

  char* ws = (char*)d_ws;
  _Float16* xf    = (_Float16*)(ws + OFF_X);
  _Float16* Wc    = (_Float16*)(ws + OFF_W);
  float*    bcomb = (float*)   (ws + OFF_B);
  _Float16* hbuf  = (_Float16*)(ws + OFF_H);
  int*      cnt   = (int*)     (ws + OFF_C);
  float*    y     = (float*)d_out;

  (void)hipMemsetAsync(ws + OFF_C, 0, 8192, stream);
  prep_x<<<4096, 256, 0, stream>>>(x, xf);
  prep_w<<<2048, 256, 0, stream>>>(Wk_f, Wr_f, Wk_b, Wr_b, b_f, b_b, Wc, bcomb);
  prep_hb<<<256, 256, 0, stream>>>(h_f, h_b, hbuf);

  static bool attr_done = false;
  if (!attr_done) {
    (void)hipFuncSetAttribute((const void*)lstm_scan,
                              hipFuncAttributeMaxDynamicSharedMemorySize, LDS_BYTES);
    attr_done = true;
  }
  lstm_scan<<<256, 256, LDS_BYTES, stream>>>(xf, Wc, bcomb, c_f, c_b, hbuf, cnt, y);
}

// Round 4
// 816.246 us; speedup vs baseline: 4.9335x; 1.6272x over previous
//
#include <hip/hip_runtime.h>
#include <hip/hip_fp16.h>
#include <cstdint>
#include <cstddef>

// Problem dims
#define B_    64
#define T_    256
#define D_    512
#define U_    500
#define UP_   512            // padded units
#define NCOL_ 2048           // 4*UP_
#define K_    1024           // D_ + UP_

typedef _Float16 f16x8 __attribute__((ext_vector_type(8)));
typedef float    f32x4 __attribute__((ext_vector_type(4)));

// ---- workspace layout (bytes) ----
#define OFF_X   0ull                         // x fp16: 64*256*512*2        = 16777216
#define OFF_W   16777216ull                  // Wcomb fp16: 2*2048*1024*2   = 8388608
#define OFF_B   25165824ull                  // bcomb f32: 2*2048*4         = 16384
#define OFF_H   25182208ull                  // h_buf fp16: 8*2*8192*2      = 262144
#define OFF_C   25444352ull                  // counters: 8*256*4           = 8192

// ---- LDS layout (bytes) ----
#define LW  0                // W slice: 64 cols * 2048B (col-major, swizzled) 128KB
#define LX0 131072           // x tile buf0: 16 rows * 1024B (swizzled) 16KB
#define LX1 147456           // x tile buf1: 16KB   (z exchange aliases consumed buf)
#define LDS_BYTES 163840

#define GLD_LDS16(g, l) \
  __builtin_amdgcn_global_load_lds((const __attribute__((address_space(1))) void*)(g), \
                                   (__attribute__((address_space(3))) void*)(l), 16, 0, 0)

// ============================ prep kernels ============================

__global__ void prep_x(const float* __restrict__ x, _Float16* __restrict__ xf) {
  size_t base = ((size_t)blockIdx.x * 256 + threadIdx.x) * 8;
  const float4* p = (const float4*)(x + base);
  float4 a = p[0], b = p[1];
  f16x8 v;
  v[0] = (_Float16)a.x; v[1] = (_Float16)a.y; v[2] = (_Float16)a.z; v[3] = (_Float16)a.w;
  v[4] = (_Float16)b.x; v[5] = (_Float16)b.y; v[6] = (_Float16)b.z; v[7] = (_Float16)b.w;
  *(f16x8*)(xf + base) = v;
}

__global__ void prep_w(const float* __restrict__ Wkf, const float* __restrict__ Wrf,
                       const float* __restrict__ Wkb, const float* __restrict__ Wrb,
                       const float* __restrict__ bf,  const float* __restrict__ bb,
                       _Float16* __restrict__ Wc, float* __restrict__ bcomb) {
  size_t gid = (size_t)blockIdx.x * 256 + threadIdx.x;
  int dir = (int)(gid >> 18);
  int rem = (int)(gid & 262143);
  int col = rem >> 7;
  int k0  = (rem & 127) << 3;
  const float* Wk = dir ? Wkb : Wkf;
  const float* Wr = dir ? Wrb : Wrf;
  int g = (col >> 4) & 3, du = col & 15, utc = col >> 6;
  int ug = utc * 16 + du;
  bool valid = (ug < U_);
  int c4 = g * U_ + ug;
  f16x8 out;
#pragma unroll
  for (int kk = 0; kk < 8; ++kk) {
    int k = k0 + kk;
    float v = 0.f;
    if (valid) {
      if (k < D_) v = Wk[(size_t)k * (4 * U_) + c4];
      else { int u = k - D_; if (u < U_) v = Wr[(size_t)u * (4 * U_) + c4]; }
    }
    out[kk] = (_Float16)v;
  }
  *(f16x8*)(Wc + ((size_t)dir * NCOL_ + col) * K_ + k0) = out;

  if (gid < 4096) {
    int d2 = (int)(gid >> 11), c2 = (int)(gid & 2047);
    int g2 = (c2 >> 4) & 3, du2 = c2 & 15, ut2 = c2 >> 6;
    int ug2 = ut2 * 16 + du2;
    const float* bs = d2 ? bb : bf;
    bcomb[gid] = (ug2 < U_) ? bs[g2 * U_ + ug2] : 0.f;
  }
}

// h_buf layout: [gi][parity][p=u>>4][row][u&15]  (512B per producer slice)
__global__ void prep_hb(const float* __restrict__ hf, const float* __restrict__ hb,
                        _Float16* __restrict__ hbuf) {
  int idx = blockIdx.x * 256 + threadIdx.x;    // < 65536
  int dir = idx >> 15;
  int rem = idx & 32767;
  int bt = rem >> 13, r = (rem >> 9) & 15, u = rem & 511;
  const float* h0 = dir ? hb : hf;
  float v = (u < U_) ? h0[(size_t)(bt * 16 + r) * U_ + u] : 0.f;
  int gi = dir * 4 + bt;
  hbuf[(size_t)(gi * 2 + 1) * 8192 + (u >> 4) * 256 + r * 16 + (u & 15)] = (_Float16)v;
}

// ============================ persistent scan ============================
__global__ __launch_bounds__(256, 1) void lstm_scan(
    const _Float16* __restrict__ xf, const _Float16* __restrict__ Wc,
    const float* __restrict__ bc, const float* __restrict__ cf,
    const float* __restrict__ cb, _Float16* __restrict__ hbuf,
    int* __restrict__ cnt, float* __restrict__ y)
{
  extern __shared__ __align__(16) char lds[];
  const int tid  = threadIdx.x;
  const int lane = tid & 63;
  const int w    = tid >> 6;        // wave id == gate id (i,f,g,o)
  const int bid  = blockIdx.x;
  const int grp  = bid & 7;         // group -> same XCD under round-robin (perf only)
  const int dir  = grp >> 2;
  const int bt   = grp & 3;
  const int ut   = bid >> 3;

  // ---- prologue: W slice -> LDS (col-major, 16B-chunk XOR swizzle) ----
  {
    const int4* wsrc = (const int4*)(Wc + ((size_t)dir * NCOL_ + (size_t)ut * 64) * K_);
    for (int it = 0; it < 32; ++it) {
      int idx = it * 256 + tid;
      int j = idx >> 7, ch = idx & 127;
      int4 v = wsrc[j * 128 + ch];
      *(int4*)(lds + LW + (size_t)j * 2048 + ((ch ^ (j & 7)) << 4)) = v;
    }
  }
  const float bias = bc[dir * NCOL_ + ut * 64 + w * 16 + (lane & 15)];
  const int r0 = tid >> 4, du0 = tid & 15;
  const int ug0 = ut * 16 + du0;
  const float* cin = dir ? cb : cf;
  float c = (ug0 < U_) ? cin[(size_t)(bt * 16 + r0) * U_ + ug0] : 0.f;

  const int gi = dir * 4 + bt;
  int* cbase = cnt + gi * 256;
  _Float16* hb = hbuf + (size_t)gi * 2 * 8192;
  const int colj = w * 16 + (lane & 15);
  const int arow = lane & 15;
  const int kg   = lane >> 4;
  const char* wcol = lds + LW + (size_t)colj * 2048;
  const int cswz = colj & 7, aswz = arow & 7;

  // stage x[0] -> buf0 (wave w stages rows 4w..4w+3)
  {
    const int t_x0 = dir ? (T_ - 1) : 0;
    for (int rr = 0; rr < 4; ++rr) {
      int r = w * 4 + rr;
      const char* src = (const char*)(xf + ((size_t)(bt * 16 + r) * T_ + t_x0) * D_)
                        + ((lane ^ (r & 7)) << 4);
      GLD_LDS16(src, lds + LX0 + r * 1024);
    }
  }

  for (int t = 0; t < T_; ++t) {
    const int t_x = dir ? (T_ - 1 - t) : t;
    const char* xbase = lds + LX0 + (t & 1) * 16384;

    // prefetch x[t+1] -> other buffer (drain folds into the poll wait)
    if (t + 1 < T_) {
      const int t_n = dir ? (T_ - 2 - t) : (t + 1);
      const char* xdst = lds + LX0 + ((t + 1) & 1) * 16384;
      for (int rr = 0; rr < 4; ++rr) {
        int r = w * 4 + rr;
        const char* src = (const char*)(xf + ((size_t)(bt * 16 + r) * T_ + t_n) * D_)
                          + ((lane ^ (r & 7)) << 4);
        GLD_LDS16(src, xdst + r * 1024);
      }
    }

    if (t > 0 && tid == 0) {
      int* cp = cbase + (t - 1);
      while (__hip_atomic_load(cp, __ATOMIC_RELAXED, __HIP_MEMORY_SCOPE_AGENT) < 32)
        __builtin_amdgcn_s_sleep(1);
    }
    __syncthreads();   // h[t-1] visible; x[t] LDS ready; prologue W done (t=0)

    // ---- h fragments: agent-coherent 8B loads, ALL issued up-front ----
    const unsigned long long* hr =
        (const unsigned long long*)(hb + (size_t)((t + 1) & 1) * 8192);
    f16x8 hfrag[16];
#pragma unroll
    for (int ks = 0; ks < 16; ++ks) {
      int ch = ks * 4 + kg;                 // k-chunk (8 units)
      int ustart = ch * 8;
      int base = (ustart >> 4) * 64 + arow * 4 + ((ustart & 15) >> 2);
      union { unsigned long long u[2]; f16x8 v; } tmp;
      tmp.u[0] = __hip_atomic_load(hr + base,     __ATOMIC_RELAXED, __HIP_MEMORY_SCOPE_AGENT);
      tmp.u[1] = __hip_atomic_load(hr + base + 1, __ATOMIC_RELAXED, __HIP_MEMORY_SCOPE_AGENT);
      hfrag[ks] = tmp.v;
    }
    __builtin_amdgcn_sched_barrier(0);      // pin: loads issued before x-MFMAs

    // ---- x-part MFMAs (LDS) — cover h-load latency ----
    f32x4 ax0 = {0.f,0.f,0.f,0.f}, ax1 = {0.f,0.f,0.f,0.f};
#pragma unroll
    for (int ks = 0; ks < 16; ++ks) {
      int ch = ks * 4 + kg;
      f16x8 a = *(const f16x8*)(xbase + arow * 1024 + ((ch ^ aswz) << 4));
      f16x8 b = *(const f16x8*)(wcol + ((ch ^ cswz) << 4));
      if (ks & 1) ax1 = __builtin_amdgcn_mfma_f32_16x16x32_f16(a, b, ax1, 0, 0, 0);
      else        ax0 = __builtin_amdgcn_mfma_f32_16x16x32_f16(a, b, ax0, 0, 0, 0);
    }
    // ---- h-part MFMAs ----
    f32x4 ah0 = {0.f,0.f,0.f,0.f}, ah1 = {0.f,0.f,0.f,0.f};
#pragma unroll
    for (int ks = 0; ks < 16; ++ks) {
      int ch = ks * 4 + kg;
      f16x8 b = *(const f16x8*)(wcol + (((64 + ch) ^ cswz) << 4));
      if (ks & 1) ah1 = __builtin_amdgcn_mfma_f32_16x16x32_f16(hfrag[ks], b, ah1, 0, 0, 0);
      else        ah0 = __builtin_amdgcn_mfma_f32_16x16x32_f16(hfrag[ks], b, ah0, 0, 0, 0);
    }
    __syncthreads();   // x buf reads done -> reuse consumed buf as z region

    float* zw = (float*)xbase;
#pragma unroll
    for (int q = 0; q < 4; ++q) {
      float zv = ax0[q] + ax1[q] + ah0[q] + ah1[q] + bias;
      zw[w * 272 + (kg * 4 + q) * 17 + (lane & 15)] = zv;
    }
    __syncthreads();

    // ---- gate combine: thread -> (row r0, unit du0), c in register ----
    float h;
    {
      const float* zr = (const float*)xbase;
      int zb = r0 * 17 + du0;
      float zi = zr[zb], zf = zr[272 + zb], zg = zr[544 + zb], zo = zr[816 + zb];
      float ig = 1.f / (1.f + __expf(-zi));
      float fg = 1.f / (1.f + __expf(-zf));
      float e2 = __expf(2.f * zg);
      float gg = (e2 - 1.f) / (e2 + 1.f);
      float og = 1.f / (1.f + __expf(-zo));
      c = fg * c + ig * gg;
      float ec = __expf(2.f * c);
      float th = (ec - 1.f) / (ec + 1.f);
      h = og * th;

      // publish h: per-producer contiguous slice [ut][r0][du0], packed 4B stores
      float hpart = __shfl_xor(h, 1, 64);
      if ((du0 & 1) == 0) {
        union { _Float16 f[2]; unsigned u; } pk;
        pk.f[0] = (_Float16)h; pk.f[1] = (_Float16)hpart;
        unsigned* hbw = (unsigned*)(hb + (size_t)(t & 1) * 8192);
        __hip_atomic_store(hbw + ((ut * 256 + r0 * 16 + du0) >> 1), pk.u,
                           __ATOMIC_RELAXED, __HIP_MEMORY_SCOPE_AGENT);
      }
    }
    __syncthreads();   // drains every wave's vmcnt -> coherent h stores complete

    if (tid == 0)
      __hip_atomic_fetch_add(cbase + t, 1, __ATOMIC_RELAXED, __HIP_MEMORY_SCOPE_AGENT);

    // y store AFTER the handoff publish (off critical path)
    if (ug0 < U_)
      y[((size_t)(bt * 16 + r0) * T_ + t_x) * (2 * U_) + dir * U_ + ug0] = h;
  }
}

// ============================ launcher ============================
extern "C" void kernel_launch(void* const* d_in, const int* in_sizes, int n_in,
                              void* d_out, int out_size, void* d_ws, size_t ws_size,
                              hipStream_t stream) {
  (void)in_sizes; (void)n_in; (void)out_size; (void)ws_size;
  const float* x    = (const float*)d_in[0];
  const float* h_f  = (const float*)d_in[1];
  const float* c_f  = (const float*)d_in[2];
  const float* h_b  = (const float*)d_in[3];
  const float* c_b  = (const float*)d_in[4];
  const float* Wk_f = (const float*)d_in[5];
  const float* Wr_f = (const float*)d_in[6];
  const float* b_f  = (const float*)d_in[7];
  const float* Wk_b = (const float*)d_in[8];
  const float* Wr_b = (const float*)d_in[9];
  const float* b_b  = (const float*)d_in[10];

  char* ws = (char*)d_ws;
  _Float16* xf    = (_Float16*)(ws + OFF_X);
  _Float16* Wc    = (_Float16*)(ws + OFF_W);
  float*    bcomb = (float*)   (ws + OFF_B);
  _Float16* hbuf  = (_Float16*)(ws + OFF_H);
  int*      cnt   = (int*)     (ws + OFF_C);
  float*    y     = (float*)d_out;

  (void)hipMemsetAsync(ws + OFF_C, 0, 8192, stream);
  prep_x<<<4096, 256, 0, stream>>>(x, xf);
  prep_w<<<2048, 256, 0, stream>>>(Wk_f, Wr_f, Wk_b, Wr_b, b_f, b_b, Wc, bcomb);
  prep_hb<<<256, 256, 0, stream>>>(h_f, h_b, hbuf);

  static bool attr_done = false;
  if (!attr_done) {
    (void)hipFuncSetAttribute((const void*)lstm_scan,
                              hipFuncAttributeMaxDynamicSharedMemorySize, LDS_BYTES);
    attr_done = true;
  }
  lstm_scan<<<256, 256, LDS_BYTES, stream>>>(xf, Wc, bcomb, c_f, c_b, hbuf, cnt, y);
}